// Round 14
// baseline (526.468 us; speedup 1.0000x reference)
//
#include <hip/hip_runtime.h>
#include <hip/hip_bf16.h>

// Problem constants (from reference)
#define NN 20000
#define EE 320000
#define FF 75
#define GG 64
#define LL 5
#define EPS 1e-5f

// GEMM paddings
#define KUV 96      // K for uv gemm (h: 75 -> 96; col 75 = 1.0 bias trick)
#define NUV 160     // cols: u at 0..74, v at 80..154
#define KPOST 384   // K for post gemm ([h|agg]: 375 -> 384)
#define KLIN 96

typedef short bf16x8 __attribute__((ext_vector_type(8)));
typedef float f32x4 __attribute__((ext_vector_type(4)));

__device__ inline void gAtomicAdd(float* p, float v) { unsafeAtomicAdd(p, v); }

__device__ inline ushort f2bs(float x) {
    __hip_bfloat16 b = __float2bfloat16(x);
    return *(ushort*)&b;
}

__device__ inline float bs2f(ushort u) {
    unsigned int x = ((unsigned int)u) << 16;
    return __uint_as_float(x);
}

// ---------------- CSR construction ----------------

__global__ void count_kernel(const int* __restrict__ col, int* __restrict__ cnt, int E) {
    int e = blockIdx.x * blockDim.x + threadIdx.x;
    if (e < E) atomicAdd(&cnt[col[e]], 1);
}

// dinv + sumlog + per-block cnt sums (merged)
__global__ void dinv_partial_kernel(const int* __restrict__ cnt, float* __restrict__ dinv,
                                    float* __restrict__ scal, int* __restrict__ bsum, int N) {
    __shared__ float red[256];
    __shared__ int redi[256];
    int tid = threadIdx.x;
    int i = blockIdx.x * 256 + tid;
    float lg = 0.f;
    int cv = 0;
    if (i < N) {
        cv = cnt[i];
        float c = (float)cv;
        dinv[i] = 1.f / sqrtf(c + 1.f);
        lg = logf(c + 1.f);
    }
    red[tid] = lg;
    redi[tid] = cv;
    __syncthreads();
    for (int s = 128; s > 0; s >>= 1) {
        if (tid < s) { red[tid] += red[tid + s]; redi[tid] += redi[tid + s]; }
        __syncthreads();
    }
    if (tid == 0) {
        gAtomicAdd(&scal[0], red[0]);
        bsum[blockIdx.x] = redi[0];
    }
}

__global__ void scanb_kernel(const int* __restrict__ bsum, int* __restrict__ bbase,
                             int* __restrict__ offs, int NB) {
    __shared__ int sh[128];
    int tid = threadIdx.x;
    int v = (tid < NB) ? bsum[tid] : 0;
    sh[tid] = v;
    __syncthreads();
    for (int d = 1; d < 128; d <<= 1) {
        int t = (tid >= d) ? sh[tid - d] : 0;
        __syncthreads();
        sh[tid] += t;
        __syncthreads();
    }
    if (tid < NB) bbase[tid] = sh[tid] - v;
    if (tid == 0) offs[NN] = EE;
}

__global__ void offs_kernel(const int* __restrict__ cnt, const int* __restrict__ bbase,
                            int* __restrict__ offs, int* __restrict__ cursor, int N) {
    __shared__ int sh[256];
    int tid = threadIdx.x;
    int i = blockIdx.x * 256 + tid;
    int v = (i < N) ? cnt[i] : 0;
    sh[tid] = v;
    __syncthreads();
    for (int d = 1; d < 256; d <<= 1) {
        int t = (tid >= d) ? sh[tid - d] : 0;
        __syncthreads();
        sh[tid] += t;
        __syncthreads();
    }
    int excl = sh[tid] - v + bbase[blockIdx.x];
    if (i < N) { offs[i] = excl; cursor[i] = excl; }
}

// CSR fill + xs prescale merged: items 0..EE-1 = fill; EE..EE+NN*80-1 = xs
__global__ void fill_xs_kernel(const int* __restrict__ row, const int* __restrict__ col,
                               int* __restrict__ cursor, int* __restrict__ csr,
                               const float* __restrict__ x, const float* __restrict__ gw,
                               const float* __restrict__ dinv, ushort* __restrict__ xs) {
    int idx = blockIdx.x * 256 + threadIdx.x;
    if (idx < EE) {
        int c = col[idx];
        int pos = atomicAdd(&cursor[c], 1);
        csr[pos] = row[idx];
    } else if (idx < EE + NN * 80) {
        int j = idx - EE;
        int n = j / 80, t = j % 80;
        float v = 0.f;
        if (t < FF) {
            float acc = 0.f;
#pragma unroll
            for (int k = 0; k < 6; k++) acc += x[n * 6 + k] * gw[k * FF + t];
            v = dinv[n] * acc;
        }
        xs[j] = f2bs(v);
    }
}

// two waves per block, one node per wave: lanes 0..39 gather ushort2, unroll 4
__global__ __launch_bounds__(128) void gcn_kernel(
    const ushort* __restrict__ xs, const float* __restrict__ dinv,
    const int* __restrict__ offs, const int* __restrict__ csr,
    const float* __restrict__ gcn_b, const int* __restrict__ cnt,
    const float* __restrict__ scal, float* __restrict__ o2,
    float* __restrict__ amp, float* __restrict__ att, int N) {
    int tid = threadIdx.x, w = tid >> 6, lane = tid & 63;
    int i = blockIdx.x * 2 + w;
    if (i >= N) return;
    int s0 = offs[i], s1 = offs[i + 1];
    if (lane < 40) {
        float a0 = 0.f, a1 = 0.f;
        int k = s0;
        for (; k + 3 < s1; k += 4) {
            int r0 = csr[k], r1 = csr[k + 1], r2 = csr[k + 2], r3 = csr[k + 3];
            ushort2 v0 = *(const ushort2*)(xs + (size_t)r0 * 80 + 2 * lane);
            ushort2 v1 = *(const ushort2*)(xs + (size_t)r1 * 80 + 2 * lane);
            ushort2 v2 = *(const ushort2*)(xs + (size_t)r2 * 80 + 2 * lane);
            ushort2 v3 = *(const ushort2*)(xs + (size_t)r3 * 80 + 2 * lane);
            a0 += (bs2f(v0.x) + bs2f(v1.x)) + (bs2f(v2.x) + bs2f(v3.x));
            a1 += (bs2f(v0.y) + bs2f(v1.y)) + (bs2f(v2.y) + bs2f(v3.y));
        }
        for (; k < s1; k++) {
            int r0 = csr[k];
            ushort2 v0 = *(const ushort2*)(xs + (size_t)r0 * 80 + 2 * lane);
            a0 += bs2f(v0.x);
            a1 += bs2f(v0.y);
        }
        ushort2 vs = *(const ushort2*)(xs + (size_t)i * 80 + 2 * lane);
        a0 += bs2f(vs.x);
        a1 += bs2f(vs.y);
        float di = dinv[i];
        int t0 = 2 * lane, t1 = 2 * lane + 1;
        if (t0 < FF) o2[(size_t)i * 80 + t0] = di * a0 + gcn_b[t0];
        if (t1 < FF) o2[(size_t)i * 80 + t1] = di * a1 + gcn_b[t1];
    } else if (lane == 63) {
        float al = scal[0] / (float)N;
        float d = fmaxf((float)cnt[i], 1.f);
        float lg = logf(d + 1.f);
        amp[i] = lg / al;
        att[i] = al / lg;
    }
}

// ---------------- B-matrix prep (bf16, transposed: BT[col][k]) ----------------

#define S_UV (LL * NUV * KUV)
#define S_POST (LL * 240 * KPOST)
#define S_LIN (LL * 80 * KLIN)

__global__ void prep_bt_kernel(const float* __restrict__ pre_w, const float* __restrict__ pre_b,
                               const float* __restrict__ post_w, const float* __restrict__ lin_w,
                               ushort* __restrict__ BTuv, ushort* __restrict__ BTpost,
                               ushort* __restrict__ BTlin) {
    int idx = blockIdx.x * 256 + threadIdx.x;
    if (idx < S_UV) {
        int l = idx / (NUV * KUV);
        int r = idx % (NUV * KUV);
        int c = r / KUV, k = r % KUV;
        float v = 0.f;
        if (k < FF) {
            if (c < FF) v = pre_w[((size_t)l * 150 + k) * FF + c];
            else if (c >= 80 && c < 80 + FF) v = pre_w[((size_t)l * 150 + FF + k) * FF + (c - 80)];
        } else if (k == FF && c < FF) {
            v = pre_b[l * FF + c];  // bias fold: A col75 = 1.0
        }
        BTuv[idx] = f2bs(v);
    } else if (idx < S_UV + S_POST) {
        int j = idx - S_UV;
        int l = j / (240 * KPOST);
        int r = j % (240 * KPOST);
        int c = r / KPOST, k = r % KPOST;
        float v = 0.f;
        if (k < FF) {
            if (c < FF) v = post_w[((size_t)l * 975 + k) * FF + c];
        } else if (k < 375) {
            if (c < FF) v = post_w[((size_t)l * 975 + k) * FF + c];
            else if (c >= 80 && c < 80 + FF) v = post_w[((size_t)l * 975 + k + 300) * FF + (c - 80)];
            else if (c >= 160 && c < 160 + FF) v = post_w[((size_t)l * 975 + k + 600) * FF + (c - 160)];
        }
        BTpost[j] = f2bs(v);
    } else if (idx < S_UV + S_POST + S_LIN) {
        int j = idx - S_UV - S_POST;
        int l = j / (80 * KLIN);
        int r = j % (80 * KLIN);
        int c = r / KLIN, k = r % KLIN;
        float v = (c < FF && k < FF) ? lin_w[((size_t)l * FF + k) * FF + c] : 0.f;
        BTlin[j] = f2bs(v);
    }
}

// ---------------- fused BN + uv GEMM (2 waves/block, 16 rows each) ----------------

__global__ __launch_bounds__(128) void uv_bn_kernel(
    const float* __restrict__ o2, const float* __restrict__ slots,
    const float* __restrict__ bg, const float* __restrict__ bb, int apply_bn,
    const ushort* __restrict__ BT, float* __restrict__ U, ushort* __restrict__ Vb,
    ushort* __restrict__ hagg) {
    __shared__ float ssL[160];
    int tid = threadIdx.x, w = tid >> 6, lane = tid & 63;
    int col16 = lane & 15, quad = lane >> 4;
    int n = blockIdx.x * 32 + w * 16 + col16;
    const float* orow = o2 + (size_t)n * 80;
    const ushort* bbase = BT + (size_t)col16 * KUV + quad * 8;

    if (apply_bn) {
        if (tid < 80) {
            int c = tid;
            if (c < FF) {
                float su = 0.f, sq = 0.f;
#pragma unroll 8
                for (int s = 0; s < 32; s++) {
                    su += slots[s * 160 + c];
                    sq += slots[s * 160 + 80 + c];
                }
                float mu = su * (1.f / (float)NN);
                float var = sq * (1.f / (float)NN) - mu * mu;
                float sc = bg[c] * rsqrtf(var + EPS);
                ssL[c] = sc;
                ssL[80 + c] = bb[c] - mu * sc;
            } else {
                ssL[c] = 0.f;
                ssL[80 + c] = 0.f;
            }
        }
        __syncthreads();
    }

    f32x4 acc[10];
#pragma unroll
    for (int i = 0; i < 10; i++) acc[i] = (f32x4){0.f, 0.f, 0.f, 0.f};

#pragma unroll
    for (int kt = 0; kt < 3; kt++) {
        int kb = kt * 32 + quad * 8;
        bf16x8 af;
        if (kb < 80) {
            float4 v0 = *(const float4*)(orow + kb);
            float4 v1 = *(const float4*)(orow + kb + 4);
            float vv[8] = {v0.x, v0.y, v0.z, v0.w, v1.x, v1.y, v1.z, v1.w};
#pragma unroll
            for (int j = 0; j < 8; j++) {
                int k = kb + j;
                float v = vv[j];
                if (apply_bn) v = fmaxf(v * ssL[k] + ssL[80 + k], 0.f);
                ushort b = (k < FF) ? f2bs(v) : (k == FF ? (ushort)0x3F80 : (ushort)0);
                af[j] = (short)b;
            }
            if (kb < FF) {
                // h-cols of hagg; forced values at cols 75..79 are overwritten by edge_agg
                *(bf16x8*)(hagg + (size_t)n * KPOST + kb) = af;
            }
        } else {
            af = (bf16x8){0, 0, 0, 0, 0, 0, 0, 0};
        }
#pragma unroll
        for (int nt = 0; nt < 10; nt++) {
            bf16x8 bfr = *(const bf16x8*)(bbase + nt * (16 * KUV) + kt * 32);
            acc[nt] = __builtin_amdgcn_mfma_f32_16x16x32_bf16(af, bfr, acc[nt], 0, 0, 0);
        }
    }
    int n0 = blockIdx.x * 32 + w * 16;
#pragma unroll
    for (int nt = 0; nt < 10; nt++) {
        int col = nt * 16 + col16;
#pragma unroll
        for (int r = 0; r < 4; r++) {
            int nn = n0 + quad * 4 + r;
            if (col < FF) U[(size_t)nn * 80 + col] = acc[nt][r];
            else if (col >= 80 && col < 80 + FF) Vb[(size_t)nn * 80 + (col - 80)] = f2bs(acc[nt][r]);
        }
    }
}

// ---------------- fused post GEMM + combine + lin GEMM + BN stats (2 waves/block) ----------------
// per-wave olds buffer -> no __syncthreads needed (wave-internal LDS ordering is HW-guaranteed)

__global__ __launch_bounds__(128) void post_lin_kernel(
    const ushort* __restrict__ A, const ushort* __restrict__ BT,
    const ushort* __restrict__ BL, const float* __restrict__ amp,
    const float* __restrict__ att, float* __restrict__ o2,
    float* __restrict__ slots) {
    __shared__ __align__(16) ushort olds[2][16 * 104];
    int tid = threadIdx.x, w = tid >> 6, lane = tid & 63;
    int col16 = lane & 15, quad = lane >> 4, kseg = quad * 8;
    int n0 = blockIdx.x * 32 + w * 16;
    ushort* oldsW = olds[w];
    const ushort* arow = A + (size_t)(n0 + col16) * KPOST + kseg;
    const ushort* bbase = BT + (size_t)col16 * KPOST + kseg;

    f32x4 acc[15];
#pragma unroll
    for (int i = 0; i < 15; i++) acc[i] = (f32x4){0.f, 0.f, 0.f, 0.f};

#pragma unroll 4
    for (int kt = 0; kt < 12; kt++) {
        bf16x8 af = *(const bf16x8*)(arow + kt * 32);
#pragma unroll
        for (int nt = 0; nt < 15; nt++) {
            bf16x8 bfr = *(const bf16x8*)(bbase + (size_t)nt * (16 * KPOST) + kt * 32);
            acc[nt] = __builtin_amdgcn_mfma_f32_16x16x32_bf16(af, bfr, acc[nt], 0, 0, 0);
        }
    }
    // combine with amp/att -> o (bf16) in per-wave LDS, A-fragment layout
    float ampv[4], attv[4];
#pragma unroll
    for (int r = 0; r < 4; r++) {
        int n = n0 + quad * 4 + r;
        ampv[r] = amp[n];
        attv[r] = att[n];
    }
#pragma unroll
    for (int g = 0; g < 5; g++) {
        int col = g * 16 + col16;
#pragma unroll
        for (int r = 0; r < 4; r++) {
            float ov = acc[g][r] + ampv[r] * acc[g + 5][r] + attv[r] * acc[g + 10][r];
            oldsW[(quad * 4 + r) * 104 + col] = (col < FF) ? f2bs(ov) : (ushort)0;
        }
    }
    // zero K-pad cols 80..95 (within-wave rows)
    *(ushort4*)(oldsW + (lane >> 2) * 104 + 80 + (lane & 3) * 4) = (ushort4){0, 0, 0, 0};

    // lin GEMM (K=96)
    f32x4 acc2[5];
#pragma unroll
    for (int i = 0; i < 5; i++) acc2[i] = (f32x4){0.f, 0.f, 0.f, 0.f};
    const ushort* blbase = BL + (size_t)col16 * KLIN + kseg;
#pragma unroll
    for (int kt = 0; kt < 3; kt++) {
        bf16x8 af = *(const bf16x8*)(oldsW + col16 * 104 + kt * 32 + kseg);
#pragma unroll
        for (int nt = 0; nt < 5; nt++) {
            bf16x8 bfr = *(const bf16x8*)(blbase + nt * (16 * KLIN) + kt * 32);
            acc2[nt] = __builtin_amdgcn_mfma_f32_16x16x32_bf16(af, bfr, acc2[nt], 0, 0, 0);
        }
    }
    // epilogue: store o2 + BN partial sums (fan into 32 slots)
    float* slot = slots + (((blockIdx.x << 1) | w) & 31) * 160;
#pragma unroll
    for (int nt = 0; nt < 5; nt++) {
        int col = nt * 16 + col16;
        float s = 0.f, q = 0.f;
#pragma unroll
        for (int r = 0; r < 4; r++) {
            int n = n0 + quad * 4 + r;
            float v = acc2[nt][r];
            if (col < FF) {
                o2[(size_t)n * 80 + col] = v;
                s += v;
                q += v * v;
            }
        }
        s += __shfl_xor(s, 16); s += __shfl_xor(s, 32);
        q += __shfl_xor(q, 16); q += __shfl_xor(q, 32);
        if (lane < 16 && col < FF) {
            gAtomicAdd(&slot[col], s);
            gAtomicAdd(&slot[80 + col], q);
        }
    }
}

// ---------------- edge aggregation: 2 waves/block, one node per wave, unroll 4 ----------------

__global__ __launch_bounds__(128) void edge_agg_kernel(
    const float* __restrict__ U, const ushort* __restrict__ V,
    const int* __restrict__ offs, const int* __restrict__ csr,
    const int* __restrict__ cnt, ushort* __restrict__ hagg, int N) {
    int tid = threadIdx.x, w = tid >> 6, lane = tid & 63;
    int i = blockIdx.x * 2 + w;
    if (i >= N) return;
    int s0 = offs[i], s1 = offs[i + 1];
    if (lane < 40) {
        float2 uiv = *(const float2*)(U + (size_t)i * 80 + 2 * lane);
        float ui0 = uiv.x, ui1 = uiv.y;
        float sa0 = 0.f, sq0 = 0.f, mn0 = 1e30f, mx0 = -1e30f;
        float sa1 = 0.f, sq1 = 0.f, mn1 = 1e30f, mx1 = -1e30f;
        int k = s0;
        for (; k + 3 < s1; k += 4) {
            int r0 = csr[k], r1 = csr[k + 1], r2 = csr[k + 2], r3 = csr[k + 3];
            ushort2 v0 = *(const ushort2*)(V + (size_t)r0 * 80 + 2 * lane);
            ushort2 v1 = *(const ushort2*)(V + (size_t)r1 * 80 + 2 * lane);
            ushort2 v2 = *(const ushort2*)(V + (size_t)r2 * 80 + 2 * lane);
            ushort2 v3 = *(const ushort2*)(V + (size_t)r3 * 80 + 2 * lane);
            float a0 = ui0 + bs2f(v0.x), b0 = ui0 + bs2f(v1.x);
            float c0 = ui0 + bs2f(v2.x), d0 = ui0 + bs2f(v3.x);
            float a1 = ui1 + bs2f(v0.y), b1 = ui1 + bs2f(v1.y);
            float c1 = ui1 + bs2f(v2.y), d1 = ui1 + bs2f(v3.y);
            sa0 += (a0 + b0) + (c0 + d0);
            sq0 += (a0 * a0 + b0 * b0) + (c0 * c0 + d0 * d0);
            mn0 = fminf(mn0, fminf(fminf(a0, b0), fminf(c0, d0)));
            mx0 = fmaxf(mx0, fmaxf(fmaxf(a0, b0), fmaxf(c0, d0)));
            sa1 += (a1 + b1) + (c1 + d1);
            sq1 += (a1 * a1 + b1 * b1) + (c1 * c1 + d1 * d1);
            mn1 = fminf(mn1, fminf(fminf(a1, b1), fminf(c1, d1)));
            mx1 = fmaxf(mx1, fmaxf(fmaxf(a1, b1), fmaxf(c1, d1)));
        }
        for (; k < s1; k++) {
            int r0 = csr[k];
            ushort2 v0 = *(const ushort2*)(V + (size_t)r0 * 80 + 2 * lane);
            float a0 = ui0 + bs2f(v0.x);
            float a1 = ui1 + bs2f(v0.y);
            sa0 += a0; sq0 += a0 * a0; mn0 = fminf(mn0, a0); mx0 = fmaxf(mx0, a0);
            sa1 += a1; sq1 += a1 * a1; mn1 = fminf(mn1, a1); mx1 = fmaxf(mx1, a1);
        }
        int c = cnt[i];
        float cc = fmaxf((float)c, 1.f);
        ushort* a = hagg + (size_t)i * KPOST + FF;
        int t0 = 2 * lane, t1 = 2 * lane + 1;
        {
            float mean = sa0 / cc;
            float stdv = sqrtf(fmaxf(sq0 / cc - mean * mean, 0.f) + EPS);
            if (c == 0) { mn0 = 0.f; mx0 = 0.f; }
            if (t0 < FF) {
                a[t0] = f2bs(mean);
                a[FF + t0] = f2bs(mn0);
                a[2 * FF + t0] = f2bs(mx0);
                a[3 * FF + t0] = f2bs(stdv);
            }
        }
        {
            float mean = sa1 / cc;
            float stdv = sqrtf(fmaxf(sq1 / cc - mean * mean, 0.f) + EPS);
            if (c == 0) { mn1 = 0.f; mx1 = 0.f; }
            if (t1 < FF) {
                a[t1] = f2bs(mean);
                a[FF + t1] = f2bs(mn1);
                a[2 * FF + t1] = f2bs(mx1);
                a[3 * FF + t1] = f2bs(stdv);
            }
        }
    } else if (lane >= 48 && lane < 57) {
        hagg[(size_t)i * KPOST + 375 + (lane - 48)] = 0;  // K-pad
    }
}

// ---------------- pooling (BN inline, slot reduce per block) + final MLP ----------------

__global__ void pool_kernel(const float* __restrict__ o2, const float* __restrict__ slots,
                            const float* __restrict__ bg, const float* __restrict__ bb,
                            const int* __restrict__ batch, float* __restrict__ g, int N) {
    __shared__ float acc[GG * FF];
    __shared__ float ssL[160];
    int tid = threadIdx.x;
    int n0 = blockIdx.x * 64;
    int n1 = min(n0 + 64, N);
    if (n0 >= N) return;
    for (int c = tid; c < 80; c += 256) {
        if (c < FF) {
            float su = 0.f, sq = 0.f;
#pragma unroll 8
            for (int s = 0; s < 32; s++) {
                su += slots[s * 160 + c];
                sq += slots[s * 160 + 80 + c];
            }
            float mu = su * (1.f / (float)NN);
            float var = sq * (1.f / (float)NN) - mu * mu;
            float sc = bg[c] * rsqrtf(var + EPS);
            ssL[c] = sc;
            ssL[80 + c] = bb[c] - mu * sc;
        } else {
            ssL[c] = 0.f;
            ssL[80 + c] = 0.f;
        }
    }
    int g0 = batch[n0];
    int g1 = batch[n1 - 1];
    int range = g1 - g0 + 1;
    for (int i = tid; i < range * FF; i += 256) acc[i] = 0.f;
    __syncthreads();
    int rows = n1 - n0;
    for (int idx = tid; idx < rows * FF; idx += 256) {
        int r = idx / FF, c = idx % FF;
        int n = n0 + r;
        float val = fmaxf(o2[(size_t)n * 80 + c] * ssL[c] + ssL[80 + c], 0.f);
        gAtomicAdd(&acc[(batch[n] - g0) * FF + c], val);
    }
    __syncthreads();
    for (int i = tid; i < range * FF; i += 256) gAtomicAdd(&g[g0 * FF + i], acc[i]);
}

__global__ void mlp_kernel(const float* __restrict__ g,
                           const float* __restrict__ w1, const float* __restrict__ b1,
                           const float* __restrict__ w2, const float* __restrict__ b2,
                           const float* __restrict__ w3, const float* __restrict__ b3,
                           float* __restrict__ out) {
    __shared__ float gr[FF], h1[50], h2[25];
    int gi = blockIdx.x, t = threadIdx.x;
    for (int j = t; j < FF; j += 64) gr[j] = g[gi * FF + j];
    __syncthreads();
    if (t < 50) {
        float a = b1[t];
        for (int k = 0; k < FF; k++) a += gr[k] * w1[k * 50 + t];
        h1[t] = fmaxf(a, 0.f);
    }
    __syncthreads();
    if (t < 25) {
        float a = b2[t];
        for (int k = 0; k < 50; k++) a += h1[k] * w2[k * 25 + t];
        h2[t] = fmaxf(a, 0.f);
    }
    __syncthreads();
    if (t < 10) {
        float a = b3[t];
        for (int k = 0; k < 25; k++) a += h2[k] * w3[k * 10 + t];
        out[gi * 10 + t] = a;
    }
}

// ---------------- launch ----------------

extern "C" void kernel_launch(void* const* d_in, const int* in_sizes, int n_in,
                              void* d_out, int out_size, void* d_ws, size_t ws_size,
                              hipStream_t stream) {
    const float* x = (const float*)d_in[0];
    const int* ei = (const int*)d_in[1];
    const int* batch = (const int*)d_in[2];
    const float* gcn_w = (const float*)d_in[3];
    const float* gcn_b = (const float*)d_in[4];
    const float* pre_w = (const float*)d_in[5];
    const float* pre_b = (const float*)d_in[6];
    const float* post_w = (const float*)d_in[7];
    const float* lin_w = (const float*)d_in[9];
    const float* bn_g = (const float*)d_in[11];
    const float* bn_b = (const float*)d_in[12];
    const float* w1 = (const float*)d_in[13];
    const float* b1 = (const float*)d_in[14];
    const float* w2 = (const float*)d_in[15];
    const float* b2 = (const float*)d_in[16];
    const float* w3 = (const float*)d_in[17];
    const float* b3 = (const float*)d_in[18];
    float* out = (float*)d_out;

    const int* row = ei;
    const int* col = ei + EE;

    char* ws = (char*)d_ws;
    size_t off = 0;
    auto alloc = [&](size_t bytes) {
        char* p = ws + off;
        off += (bytes + 255) & ~(size_t)255;
        return p;
    };
    int* cnt = (int*)alloc(NN * 4);
    int* offs = (int*)alloc((NN + 1) * 4);
    int* cursor = (int*)alloc(NN * 4);
    int* csr = (int*)alloc(EE * 4);
    int* bsum = (int*)alloc(128 * 4);
    int* bbase = (int*)alloc(128 * 4);
    float* dinv = (float*)alloc(NN * 4);
    float* amp = (float*)alloc(NN * 4);
    float* att = (float*)alloc(NN * 4);
    // scal: [0]=sumlog; slots[5][32][160]
    float* scal = (float*)alloc((1 + LL * 32 * 160) * 4);
    float* slotbase = scal + 1;
    float* o2 = (float*)alloc((size_t)NN * 80 * 4);
    float* ubuf = (float*)alloc((size_t)NN * 80 * 4);
    ushort* vbuf = (ushort*)alloc((size_t)NN * 80 * 2);  // xs in setup, V in layers
    ushort* hagg = (ushort*)alloc((size_t)NN * KPOST * 2);
    ushort* BTuv = (ushort*)alloc((size_t)S_UV * 2);
    ushort* BTpost = (ushort*)alloc((size_t)S_POST * 2);
    ushort* BTlin = (ushort*)alloc((size_t)S_LIN * 2);
    float* gbuf = (float*)alloc(GG * FF * 4);

    hipMemsetAsync(cnt, 0, NN * 4, stream);
    hipMemsetAsync(scal, 0, (1 + LL * 32 * 160) * 4, stream);
    hipMemsetAsync(gbuf, 0, GG * FF * 4, stream);

    const int B = 256;
    const int NB = (NN + 255) / 256;  // 79
    count_kernel<<<(EE + B - 1) / B, B, 0, stream>>>(col, cnt, EE);
    dinv_partial_kernel<<<NB, B, 0, stream>>>(cnt, dinv, scal, bsum, NN);
    scanb_kernel<<<1, 128, 0, stream>>>(bsum, bbase, offs, NB);
    offs_kernel<<<NB, B, 0, stream>>>(cnt, bbase, offs, cursor, NN);
    fill_xs_kernel<<<(EE + NN * 80 + B - 1) / B, B, 0, stream>>>(row, col, cursor, csr,
                                                                 x, gcn_w, dinv, vbuf);
    gcn_kernel<<<NN / 2, 128, 0, stream>>>(vbuf, dinv, offs, csr, gcn_b, cnt, scal,
                                           o2, amp, att, NN);
    {
        int tot = S_UV + S_POST + S_LIN;
        prep_bt_kernel<<<(tot + B - 1) / B, B, 0, stream>>>(pre_w, pre_b, post_w, lin_w,
                                                            BTuv, BTpost, BTlin);
    }

    const int GS2 = NN / 32;  // 625 two-wave blocks (exact)
    for (int l = 0; l < LL; l++) {
        float* slots_prev = slotbase + (l - 1) * 32 * 160;  // unused when l==0
        float* slots = slotbase + l * 32 * 160;
        int lp = (l > 0) ? (l - 1) : 0;
        int ab = (l > 0) ? 1 : 0;
        const float* sp = (l == 0) ? slotbase : slots_prev;

        uv_bn_kernel<<<GS2, 128, 0, stream>>>(o2, sp, bn_g + lp * FF, bn_b + lp * FF, ab,
                                              BTuv + (size_t)l * NUV * KUV, ubuf, vbuf, hagg);
        edge_agg_kernel<<<NN / 2, 128, 0, stream>>>(ubuf, vbuf, offs, csr, cnt, hagg, NN);
        post_lin_kernel<<<GS2, 128, 0, stream>>>(hagg, BTpost + (size_t)l * 240 * KPOST,
                                                 BTlin + (size_t)l * 80 * KLIN, amp, att,
                                                 o2, slots);
    }

    pool_kernel<<<(NN + 63) / 64, 256, 0, stream>>>(o2, slotbase + (LL - 1) * 32 * 160,
                                                    bn_g + (LL - 1) * FF, bn_b + (LL - 1) * FF,
                                                    batch, gbuf, NN);
    mlp_kernel<<<GG, 64, 0, stream>>>(gbuf, w1, b1, w2, b2, w3, b3, out);
}

// Round 15
// 496.456 us; speedup vs baseline: 1.0605x; 1.0605x over previous
//
#include <hip/hip_runtime.h>
#include <hip/hip_bf16.h>

// Problem constants (from reference)
#define NN 20000
#define EE 320000
#define FF 75
#define GG 64
#define LL 5
#define EPS 1e-5f

// GEMM paddings
#define KUV 96      // K for uv gemm (h: 75 -> 96; col 75 = 1.0 bias trick)
#define NUV 160     // cols: u at 0..74, v at 80..154
#define KPOST 384   // K for post gemm ([h|agg]: 375 -> 384)
#define KLIN 96

typedef short bf16x8 __attribute__((ext_vector_type(8)));
typedef float f32x4 __attribute__((ext_vector_type(4)));

__device__ inline void gAtomicAdd(float* p, float v) { unsafeAtomicAdd(p, v); }

__device__ inline ushort f2bs(float x) {
    __hip_bfloat16 b = __float2bfloat16(x);
    return *(ushort*)&b;
}

__device__ inline float bs2f(ushort u) {
    unsigned int x = ((unsigned int)u) << 16;
    return __uint_as_float(x);
}

// ---------------- CSR construction ----------------

__global__ void count_kernel(const int* __restrict__ col, int* __restrict__ cnt, int E) {
    int e = blockIdx.x * blockDim.x + threadIdx.x;
    if (e < E) atomicAdd(&cnt[col[e]], 1);
}

// dinv + sumlog + per-block cnt sums (merged)
__global__ void dinv_partial_kernel(const int* __restrict__ cnt, float* __restrict__ dinv,
                                    float* __restrict__ scal, int* __restrict__ bsum, int N) {
    __shared__ float red[256];
    __shared__ int redi[256];
    int tid = threadIdx.x;
    int i = blockIdx.x * 256 + tid;
    float lg = 0.f;
    int cv = 0;
    if (i < N) {
        cv = cnt[i];
        float c = (float)cv;
        dinv[i] = 1.f / sqrtf(c + 1.f);
        lg = logf(c + 1.f);
    }
    red[tid] = lg;
    redi[tid] = cv;
    __syncthreads();
    for (int s = 128; s > 0; s >>= 1) {
        if (tid < s) { red[tid] += red[tid + s]; redi[tid] += redi[tid + s]; }
        __syncthreads();
    }
    if (tid == 0) {
        gAtomicAdd(&scal[0], red[0]);
        bsum[blockIdx.x] = redi[0];
    }
}

__global__ void scanb_kernel(const int* __restrict__ bsum, int* __restrict__ bbase,
                             int* __restrict__ offs, int NB) {
    __shared__ int sh[128];
    int tid = threadIdx.x;
    int v = (tid < NB) ? bsum[tid] : 0;
    sh[tid] = v;
    __syncthreads();
    for (int d = 1; d < 128; d <<= 1) {
        int t = (tid >= d) ? sh[tid - d] : 0;
        __syncthreads();
        sh[tid] += t;
        __syncthreads();
    }
    if (tid < NB) bbase[tid] = sh[tid] - v;
    if (tid == 0) offs[NN] = EE;
}

__global__ void offs_kernel(const int* __restrict__ cnt, const int* __restrict__ bbase,
                            int* __restrict__ offs, int* __restrict__ cursor, int N) {
    __shared__ int sh[256];
    int tid = threadIdx.x;
    int i = blockIdx.x * 256 + tid;
    int v = (i < N) ? cnt[i] : 0;
    sh[tid] = v;
    __syncthreads();
    for (int d = 1; d < 256; d <<= 1) {
        int t = (tid >= d) ? sh[tid - d] : 0;
        __syncthreads();
        sh[tid] += t;
        __syncthreads();
    }
    int excl = sh[tid] - v + bbase[blockIdx.x];
    if (i < N) { offs[i] = excl; cursor[i] = excl; }
}

// CSR fill + xs prescale merged: items 0..EE-1 = fill; EE..EE+NN*80-1 = xs
__global__ void fill_xs_kernel(const int* __restrict__ row, const int* __restrict__ col,
                               int* __restrict__ cursor, int* __restrict__ csr,
                               const float* __restrict__ x, const float* __restrict__ gw,
                               const float* __restrict__ dinv, ushort* __restrict__ xs) {
    int idx = blockIdx.x * 256 + threadIdx.x;
    if (idx < EE) {
        int c = col[idx];
        int pos = atomicAdd(&cursor[c], 1);
        csr[pos] = row[idx];
    } else if (idx < EE + NN * 80) {
        int j = idx - EE;
        int n = j / 80, t = j % 80;
        float v = 0.f;
        if (t < FF) {
            float acc = 0.f;
#pragma unroll
            for (int k = 0; k < 6; k++) acc += x[n * 6 + k] * gw[k * FF + t];
            v = dinv[n] * acc;
        }
        xs[j] = f2bs(v);
    }
}

// one wave per node: lanes 0..39 gather ushort2 (features 2l, 2l+1), unroll 8
__global__ __launch_bounds__(64) void gcn_kernel(
    const ushort* __restrict__ xs, const float* __restrict__ dinv,
    const int* __restrict__ offs, const int* __restrict__ csr,
    const float* __restrict__ gcn_b, const int* __restrict__ cnt,
    const float* __restrict__ scal, float* __restrict__ o2,
    float* __restrict__ amp, float* __restrict__ att, int N) {
    int i = blockIdx.x;
    int lane = threadIdx.x;
    int s0 = offs[i], s1 = offs[i + 1];
    if (lane < 40) {
        float a0 = 0.f, a1 = 0.f;
        int k = s0;
        for (; k + 7 < s1; k += 8) {
            int rr[8];
#pragma unroll
            for (int j = 0; j < 8; j++) rr[j] = csr[k + j];
#pragma unroll
            for (int j = 0; j < 8; j++) {
                ushort2 v = *(const ushort2*)(xs + (size_t)rr[j] * 80 + 2 * lane);
                a0 += bs2f(v.x);
                a1 += bs2f(v.y);
            }
        }
        for (; k < s1; k++) {
            int r0 = csr[k];
            ushort2 v0 = *(const ushort2*)(xs + (size_t)r0 * 80 + 2 * lane);
            a0 += bs2f(v0.x);
            a1 += bs2f(v0.y);
        }
        ushort2 vs = *(const ushort2*)(xs + (size_t)i * 80 + 2 * lane);
        a0 += bs2f(vs.x);
        a1 += bs2f(vs.y);
        float di = dinv[i];
        int t0 = 2 * lane, t1 = 2 * lane + 1;
        if (t0 < FF) o2[(size_t)i * 80 + t0] = di * a0 + gcn_b[t0];
        if (t1 < FF) o2[(size_t)i * 80 + t1] = di * a1 + gcn_b[t1];
    } else if (lane == 63) {
        float al = scal[0] / (float)N;
        float d = fmaxf((float)cnt[i], 1.f);
        float lg = logf(d + 1.f);
        amp[i] = lg / al;
        att[i] = al / lg;
    }
}

// ---------------- B-matrix prep (bf16, transposed: BT[col][k]) ----------------

#define S_UV (LL * NUV * KUV)
#define S_POST (LL * 240 * KPOST)
#define S_LIN (LL * 80 * KLIN)

__global__ void prep_bt_kernel(const float* __restrict__ pre_w, const float* __restrict__ pre_b,
                               const float* __restrict__ post_w, const float* __restrict__ lin_w,
                               ushort* __restrict__ BTuv, ushort* __restrict__ BTpost,
                               ushort* __restrict__ BTlin) {
    int idx = blockIdx.x * 256 + threadIdx.x;
    if (idx < S_UV) {
        int l = idx / (NUV * KUV);
        int r = idx % (NUV * KUV);
        int c = r / KUV, k = r % KUV;
        float v = 0.f;
        if (k < FF) {
            if (c < FF) v = pre_w[((size_t)l * 150 + k) * FF + c];
            else if (c >= 80 && c < 80 + FF) v = pre_w[((size_t)l * 150 + FF + k) * FF + (c - 80)];
        } else if (k == FF && c < FF) {
            v = pre_b[l * FF + c];  // bias fold: A col75 = 1.0
        }
        BTuv[idx] = f2bs(v);
    } else if (idx < S_UV + S_POST) {
        int j = idx - S_UV;
        int l = j / (240 * KPOST);
        int r = j % (240 * KPOST);
        int c = r / KPOST, k = r % KPOST;
        float v = 0.f;
        if (k < FF) {
            if (c < FF) v = post_w[((size_t)l * 975 + k) * FF + c];
        } else if (k < 375) {
            if (c < FF) v = post_w[((size_t)l * 975 + k) * FF + c];
            else if (c >= 80 && c < 80 + FF) v = post_w[((size_t)l * 975 + k + 300) * FF + (c - 80)];
            else if (c >= 160 && c < 160 + FF) v = post_w[((size_t)l * 975 + k + 600) * FF + (c - 160)];
        }
        BTpost[j] = f2bs(v);
    } else if (idx < S_UV + S_POST + S_LIN) {
        int j = idx - S_UV - S_POST;
        int l = j / (80 * KLIN);
        int r = j % (80 * KLIN);
        int c = r / KLIN, k = r % KLIN;
        float v = (c < FF && k < FF) ? lin_w[((size_t)l * FF + k) * FF + c] : 0.f;
        BTlin[j] = f2bs(v);
    }
}

// ---------------- fused BN + uv GEMM (streaming, 1 wave = 16 rows) ----------------
// BN scale/shift computed per-block from the 32 stat slots of the PREVIOUS layer.

__global__ __launch_bounds__(64) void uv_bn_kernel(
    const float* __restrict__ o2, const float* __restrict__ slots,
    const float* __restrict__ bg, const float* __restrict__ bb, int apply_bn,
    const ushort* __restrict__ BT, float* __restrict__ U, ushort* __restrict__ Vb,
    ushort* __restrict__ hagg) {
    __shared__ float ssL[160];
    int lane = threadIdx.x;
    int col16 = lane & 15, quad = lane >> 4;
    int n = blockIdx.x * 16 + col16;
    const float* orow = o2 + (size_t)n * 80;
    const ushort* bbase = BT + (size_t)col16 * KUV + quad * 8;

    if (apply_bn) {
        for (int c = lane; c < 80; c += 64) {
            if (c < FF) {
                float su = 0.f, sq = 0.f;
#pragma unroll 8
                for (int s = 0; s < 32; s++) {
                    su += slots[s * 160 + c];
                    sq += slots[s * 160 + 80 + c];
                }
                float mu = su * (1.f / (float)NN);
                float var = sq * (1.f / (float)NN) - mu * mu;
                float sc = bg[c] * rsqrtf(var + EPS);
                ssL[c] = sc;
                ssL[80 + c] = bb[c] - mu * sc;
            } else {
                ssL[c] = 0.f;
                ssL[80 + c] = 0.f;
            }
        }
        __syncthreads();
    }

    f32x4 acc[10];
#pragma unroll
    for (int i = 0; i < 10; i++) acc[i] = (f32x4){0.f, 0.f, 0.f, 0.f};

#pragma unroll
    for (int kt = 0; kt < 3; kt++) {
        int kb = kt * 32 + quad * 8;
        bf16x8 af;
        if (kb < 80) {
            float4 v0 = *(const float4*)(orow + kb);
            float4 v1 = *(const float4*)(orow + kb + 4);
            float vv[8] = {v0.x, v0.y, v0.z, v0.w, v1.x, v1.y, v1.z, v1.w};
#pragma unroll
            for (int j = 0; j < 8; j++) {
                int k = kb + j;
                float v = vv[j];
                if (apply_bn) v = fmaxf(v * ssL[k] + ssL[80 + k], 0.f);
                ushort b = (k < FF) ? f2bs(v) : (k == FF ? (ushort)0x3F80 : (ushort)0);
                af[j] = (short)b;
            }
            if (kb < FF) {
                // h-cols of hagg; forced values at cols 75..79 are overwritten by edge_agg
                *(bf16x8*)(hagg + (size_t)n * KPOST + kb) = af;
            }
        } else {
            af = (bf16x8){0, 0, 0, 0, 0, 0, 0, 0};
        }
#pragma unroll
        for (int nt = 0; nt < 10; nt++) {
            bf16x8 bfr = *(const bf16x8*)(bbase + nt * (16 * KUV) + kt * 32);
            acc[nt] = __builtin_amdgcn_mfma_f32_16x16x32_bf16(af, bfr, acc[nt], 0, 0, 0);
        }
    }
    int n0 = blockIdx.x * 16;
#pragma unroll
    for (int nt = 0; nt < 10; nt++) {
        int col = nt * 16 + col16;
#pragma unroll
        for (int r = 0; r < 4; r++) {
            int nn = n0 + quad * 4 + r;
            if (col < FF) U[(size_t)nn * 80 + col] = acc[nt][r];
            else if (col >= 80 && col < 80 + FF) Vb[(size_t)nn * 80 + (col - 80)] = f2bs(acc[nt][r]);
        }
    }
}

// ---------------- fused post GEMM + combine + lin GEMM + BN stats (1 wave) ----------------

__global__ __launch_bounds__(64) void post_lin_kernel(
    const ushort* __restrict__ A, const ushort* __restrict__ BT,
    const ushort* __restrict__ BL, const float* __restrict__ amp,
    const float* __restrict__ att, float* __restrict__ o2,
    float* __restrict__ slots) {
    __shared__ __align__(16) ushort olds[16 * 104];
    int lane = threadIdx.x;
    int col16 = lane & 15, quad = lane >> 4, kseg = quad * 8;
    int n0 = blockIdx.x * 16;
    const ushort* arow = A + (size_t)(n0 + col16) * KPOST + kseg;
    const ushort* bbase = BT + (size_t)col16 * KPOST + kseg;

    f32x4 acc[15];
#pragma unroll
    for (int i = 0; i < 15; i++) acc[i] = (f32x4){0.f, 0.f, 0.f, 0.f};

#pragma unroll 4
    for (int kt = 0; kt < 12; kt++) {
        bf16x8 af = *(const bf16x8*)(arow + kt * 32);
#pragma unroll
        for (int nt = 0; nt < 15; nt++) {
            bf16x8 bfr = *(const bf16x8*)(bbase + (size_t)nt * (16 * KPOST) + kt * 32);
            acc[nt] = __builtin_amdgcn_mfma_f32_16x16x32_bf16(af, bfr, acc[nt], 0, 0, 0);
        }
    }
    // combine with amp/att -> o (bf16) in LDS, A-fragment layout
    float ampv[4], attv[4];
#pragma unroll
    for (int r = 0; r < 4; r++) {
        int n = n0 + quad * 4 + r;
        ampv[r] = amp[n];
        attv[r] = att[n];
    }
#pragma unroll
    for (int g = 0; g < 5; g++) {
        int col = g * 16 + col16;
#pragma unroll
        for (int r = 0; r < 4; r++) {
            float ov = acc[g][r] + ampv[r] * acc[g + 5][r] + attv[r] * acc[g + 10][r];
            olds[(quad * 4 + r) * 104 + col] = (col < FF) ? f2bs(ov) : (ushort)0;
        }
    }
    // zero K-pad cols 80..95
    *(ushort4*)(olds + (lane >> 2) * 104 + 80 + (lane & 3) * 4) = (ushort4){0, 0, 0, 0};
    __syncthreads();

    // lin GEMM (K=96)
    f32x4 acc2[5];
#pragma unroll
    for (int i = 0; i < 5; i++) acc2[i] = (f32x4){0.f, 0.f, 0.f, 0.f};
    const ushort* blbase = BL + (size_t)col16 * KLIN + kseg;
#pragma unroll
    for (int kt = 0; kt < 3; kt++) {
        bf16x8 af = *(const bf16x8*)(olds + col16 * 104 + kt * 32 + kseg);
#pragma unroll
        for (int nt = 0; nt < 5; nt++) {
            bf16x8 bfr = *(const bf16x8*)(blbase + nt * (16 * KLIN) + kt * 32);
            acc2[nt] = __builtin_amdgcn_mfma_f32_16x16x32_bf16(af, bfr, acc2[nt], 0, 0, 0);
        }
    }
    // epilogue: store o2 + BN partial sums (fan into 32 slots)
    float* slot = slots + (blockIdx.x & 31) * 160;
#pragma unroll
    for (int nt = 0; nt < 5; nt++) {
        int col = nt * 16 + col16;
        float s = 0.f, q = 0.f;
#pragma unroll
        for (int r = 0; r < 4; r++) {
            int n = n0 + quad * 4 + r;
            float v = acc2[nt][r];
            if (col < FF) {
                o2[(size_t)n * 80 + col] = v;
                s += v;
                q += v * v;
            }
        }
        s += __shfl_xor(s, 16); s += __shfl_xor(s, 32);
        q += __shfl_xor(q, 16); q += __shfl_xor(q, 32);
        if (lane < 16 && col < FF) {
            gAtomicAdd(&slot[col], s);
            gAtomicAdd(&slot[80 + col], q);
        }
    }
}

// ---------------- edge aggregation: one wave per node, ushort2 gathers, unroll 8 ----------------

__global__ __launch_bounds__(64) void edge_agg_kernel(
    const float* __restrict__ U, const ushort* __restrict__ V,
    const int* __restrict__ offs, const int* __restrict__ csr,
    const int* __restrict__ cnt, ushort* __restrict__ hagg) {
    int i = blockIdx.x;
    int lane = threadIdx.x;
    int s0 = offs[i], s1 = offs[i + 1];
    if (lane < 40) {
        float2 uiv = *(const float2*)(U + (size_t)i * 80 + 2 * lane);
        float ui0 = uiv.x, ui1 = uiv.y;
        float sa0 = 0.f, sq0 = 0.f, mn0 = 1e30f, mx0 = -1e30f;
        float sa1 = 0.f, sq1 = 0.f, mn1 = 1e30f, mx1 = -1e30f;
        int k = s0;
        for (; k + 7 < s1; k += 8) {
            int rr[8];
#pragma unroll
            for (int j = 0; j < 8; j++) rr[j] = csr[k + j];
#pragma unroll
            for (int j = 0; j < 8; j++) {
                ushort2 v = *(const ushort2*)(V + (size_t)rr[j] * 80 + 2 * lane);
                float m0 = ui0 + bs2f(v.x);
                float m1 = ui1 + bs2f(v.y);
                sa0 += m0; sq0 += m0 * m0; mn0 = fminf(mn0, m0); mx0 = fmaxf(mx0, m0);
                sa1 += m1; sq1 += m1 * m1; mn1 = fminf(mn1, m1); mx1 = fmaxf(mx1, m1);
            }
        }
        for (; k < s1; k++) {
            int r0 = csr[k];
            ushort2 v0 = *(const ushort2*)(V + (size_t)r0 * 80 + 2 * lane);
            float a0 = ui0 + bs2f(v0.x);
            float a1 = ui1 + bs2f(v0.y);
            sa0 += a0; sq0 += a0 * a0; mn0 = fminf(mn0, a0); mx0 = fmaxf(mx0, a0);
            sa1 += a1; sq1 += a1 * a1; mn1 = fminf(mn1, a1); mx1 = fmaxf(mx1, a1);
        }
        int c = cnt[i];
        float cc = fmaxf((float)c, 1.f);
        ushort* a = hagg + (size_t)i * KPOST + FF;
        int t0 = 2 * lane, t1 = 2 * lane + 1;
        {
            float mean = sa0 / cc;
            float stdv = sqrtf(fmaxf(sq0 / cc - mean * mean, 0.f) + EPS);
            if (c == 0) { mn0 = 0.f; mx0 = 0.f; }
            if (t0 < FF) {
                a[t0] = f2bs(mean);
                a[FF + t0] = f2bs(mn0);
                a[2 * FF + t0] = f2bs(mx0);
                a[3 * FF + t0] = f2bs(stdv);
            }
        }
        {
            float mean = sa1 / cc;
            float stdv = sqrtf(fmaxf(sq1 / cc - mean * mean, 0.f) + EPS);
            if (c == 0) { mn1 = 0.f; mx1 = 0.f; }
            if (t1 < FF) {
                a[t1] = f2bs(mean);
                a[FF + t1] = f2bs(mn1);
                a[2 * FF + t1] = f2bs(mx1);
                a[3 * FF + t1] = f2bs(stdv);
            }
        }
    } else if (lane >= 48 && lane < 57) {
        hagg[(size_t)i * KPOST + 375 + (lane - 48)] = 0;  // K-pad
    }
}

// ---------------- fused pooling (BN inline) + per-group MLP ----------------
// one block per graph/group; sorted batch -> binary search the node range.

__global__ __launch_bounds__(256) void pool_mlp_kernel(
    const float* __restrict__ o2, const float* __restrict__ slots,
    const float* __restrict__ bg, const float* __restrict__ bb,
    const int* __restrict__ batch,
    const float* __restrict__ w1, const float* __restrict__ b1,
    const float* __restrict__ w2, const float* __restrict__ b2,
    const float* __restrict__ w3, const float* __restrict__ b3,
    float* __restrict__ out) {
    __shared__ float ssL[160];
    __shared__ float part[240];
    __shared__ float gr[FF], h1[50], h2[25];
    __shared__ int sbound[2];
    int tid = threadIdx.x;
    int g = blockIdx.x;

    if (tid < 80) {
        int c = tid;
        if (c < FF) {
            float su = 0.f, sq = 0.f;
#pragma unroll 8
            for (int s = 0; s < 32; s++) {
                su += slots[s * 160 + c];
                sq += slots[s * 160 + 80 + c];
            }
            float mu = su * (1.f / (float)NN);
            float var = sq * (1.f / (float)NN) - mu * mu;
            float sc = bg[c] * rsqrtf(var + EPS);
            ssL[c] = sc;
            ssL[80 + c] = bb[c] - mu * sc;
        }
    } else if (tid == 128) {
        int lo = 0, hi = NN;
        while (lo < hi) { int mid = (lo + hi) >> 1; if (batch[mid] < g) lo = mid + 1; else hi = mid; }
        sbound[0] = lo;
        lo = 0; hi = NN;
        while (lo < hi) { int mid = (lo + hi) >> 1; if (batch[mid] < g + 1) lo = mid + 1; else hi = mid; }
        sbound[1] = lo;
    }
    __syncthreads();
    int s0p = sbound[0], s1p = sbound[1];

    if (tid < 240) {
        int c = tid % 80, seg = tid / 80;
        float p = 0.f;
        if (c < FF) {
            for (int r = s0p + seg; r < s1p; r += 3)
                p += fmaxf(o2[(size_t)r * 80 + c] * ssL[c] + ssL[80 + c], 0.f);
        }
        part[tid] = p;
    }
    __syncthreads();
    if (tid < FF) gr[tid] = part[tid] + part[80 + tid] + part[160 + tid];
    __syncthreads();
    if (tid < 50) {
        float a = b1[tid];
        for (int k = 0; k < FF; k++) a += gr[k] * w1[k * 50 + tid];
        h1[tid] = fmaxf(a, 0.f);
    }
    __syncthreads();
    if (tid < 25) {
        float a = b2[tid];
        for (int k = 0; k < 50; k++) a += h1[k] * w2[k * 25 + tid];
        h2[tid] = fmaxf(a, 0.f);
    }
    __syncthreads();
    if (tid < 10) {
        float a = b3[tid];
        for (int k = 0; k < 25; k++) a += h2[k] * w3[k * 10 + tid];
        out[g * 10 + tid] = a;
    }
}

// ---------------- launch ----------------

extern "C" void kernel_launch(void* const* d_in, const int* in_sizes, int n_in,
                              void* d_out, int out_size, void* d_ws, size_t ws_size,
                              hipStream_t stream) {
    const float* x = (const float*)d_in[0];
    const int* ei = (const int*)d_in[1];
    const int* batch = (const int*)d_in[2];
    const float* gcn_w = (const float*)d_in[3];
    const float* gcn_b = (const float*)d_in[4];
    const float* pre_w = (const float*)d_in[5];
    const float* pre_b = (const float*)d_in[6];
    const float* post_w = (const float*)d_in[7];
    const float* lin_w = (const float*)d_in[9];
    const float* bn_g = (const float*)d_in[11];
    const float* bn_b = (const float*)d_in[12];
    const float* w1 = (const float*)d_in[13];
    const float* b1 = (const float*)d_in[14];
    const float* w2 = (const float*)d_in[15];
    const float* b2 = (const float*)d_in[16];
    const float* w3 = (const float*)d_in[17];
    const float* b3 = (const float*)d_in[18];
    float* out = (float*)d_out;

    const int* row = ei;
    const int* col = ei + EE;

    char* ws = (char*)d_ws;
    size_t off = 0;
    auto alloc = [&](size_t bytes) {
        char* p = ws + off;
        off += (bytes + 255) & ~(size_t)255;
        return p;
    };
    // zero-region: cnt + scal adjacent, single memset
    size_t z0 = off;
    int* cnt = (int*)alloc(NN * 4);
    float* scal = (float*)alloc((1 + LL * 32 * 160) * 4);  // [0]=sumlog; slots[5][32][160]
    size_t z1 = off;
    float* slotbase = scal + 1;
    int* offs = (int*)alloc((NN + 1) * 4);
    int* cursor = (int*)alloc(NN * 4);
    int* csr = (int*)alloc(EE * 4);
    int* bsum = (int*)alloc(128 * 4);
    int* bbase = (int*)alloc(128 * 4);
    float* dinv = (float*)alloc(NN * 4);
    float* amp = (float*)alloc(NN * 4);
    float* att = (float*)alloc(NN * 4);
    float* o2 = (float*)alloc((size_t)NN * 80 * 4);
    float* ubuf = (float*)alloc((size_t)NN * 80 * 4);
    ushort* vbuf = (ushort*)alloc((size_t)NN * 80 * 2);  // xs in setup, V in layers
    ushort* hagg = (ushort*)alloc((size_t)NN * KPOST * 2);
    ushort* BTuv = (ushort*)alloc((size_t)S_UV * 2);
    ushort* BTpost = (ushort*)alloc((size_t)S_POST * 2);
    ushort* BTlin = (ushort*)alloc((size_t)S_LIN * 2);

    hipMemsetAsync(ws + z0, 0, z1 - z0, stream);

    const int B = 256;
    const int NB = (NN + 255) / 256;  // 79
    count_kernel<<<(EE + B - 1) / B, B, 0, stream>>>(col, cnt, EE);
    dinv_partial_kernel<<<NB, B, 0, stream>>>(cnt, dinv, scal, bsum, NN);
    scanb_kernel<<<1, 128, 0, stream>>>(bsum, bbase, offs, NB);
    offs_kernel<<<NB, B, 0, stream>>>(cnt, bbase, offs, cursor, NN);
    fill_xs_kernel<<<(EE + NN * 80 + B - 1) / B, B, 0, stream>>>(row, col, cursor, csr,
                                                                 x, gcn_w, dinv, vbuf);
    gcn_kernel<<<NN, 64, 0, stream>>>(vbuf, dinv, offs, csr, gcn_b, cnt, scal,
                                      o2, amp, att, NN);
    {
        int tot = S_UV + S_POST + S_LIN;
        prep_bt_kernel<<<(tot + B - 1) / B, B, 0, stream>>>(pre_w, pre_b, post_w, lin_w,
                                                            BTuv, BTpost, BTlin);
    }

    const int GS = NN / 16;  // 1250 single-wave blocks (exact)
    for (int l = 0; l < LL; l++) {
        float* slots_prev = slotbase + (l - 1) * 32 * 160;  // unused when l==0
        float* slots = slotbase + l * 32 * 160;
        int lp = (l > 0) ? (l - 1) : 0;
        int ab = (l > 0) ? 1 : 0;
        const float* sp = (l == 0) ? slotbase : slots_prev;

        uv_bn_kernel<<<GS, 64, 0, stream>>>(o2, sp, bn_g + lp * FF, bn_b + lp * FF, ab,
                                            BTuv + (size_t)l * NUV * KUV, ubuf, vbuf, hagg);
        edge_agg_kernel<<<NN, 64, 0, stream>>>(ubuf, vbuf, offs, csr, cnt, hagg);
        post_lin_kernel<<<GS, 64, 0, stream>>>(hagg, BTpost + (size_t)l * 240 * KPOST,
                                               BTlin + (size_t)l * 80 * KLIN, amp, att,
                                               o2, slots);
    }

    pool_mlp_kernel<<<GG, 256, 0, stream>>>(o2, slotbase + (LL - 1) * 32 * 160,
                                            bn_g + (LL - 1) * FF, bn_b + (LL - 1) * FF,
                                            batch, w1, b1, w2, b2, w3, b3, out);
}

// Round 16
// 482.102 us; speedup vs baseline: 1.0920x; 1.0298x over previous
//
#include <hip/hip_runtime.h>
#include <hip/hip_bf16.h>

// Problem constants (from reference)
#define NN 20000
#define EE 320000
#define FF 75
#define GG 64
#define LL 5
#define EPS 1e-5f

// GEMM paddings
#define KUV 96      // K for uv gemm (h: 75 -> 96; col 75 = 1.0 bias trick)
#define NUV 160     // cols: u at 0..74, v at 80..154
#define KPOST 384   // K for post gemm ([h|agg]: 375 -> 384)
#define KLIN 96

typedef short bf16x8 __attribute__((ext_vector_type(8)));
typedef float f32x4 __attribute__((ext_vector_type(4)));

__device__ inline void gAtomicAdd(float* p, float v) { unsafeAtomicAdd(p, v); }

__device__ inline ushort f2bs(float x) {
    __hip_bfloat16 b = __float2bfloat16(x);
    return *(ushort*)&b;
}

__device__ inline float bs2f(ushort u) {
    unsigned int x = ((unsigned int)u) << 16;
    return __uint_as_float(x);
}

// ---------------- CSR construction ----------------

__global__ void count_kernel(const int* __restrict__ col, int* __restrict__ cnt, int E) {
    int e = blockIdx.x * blockDim.x + threadIdx.x;
    if (e < E) atomicAdd(&cnt[col[e]], 1);
}

// dinv + sumlog + per-block cnt sums (merged)
__global__ void dinv_partial_kernel(const int* __restrict__ cnt, float* __restrict__ dinv,
                                    float* __restrict__ scal, int* __restrict__ bsum, int N) {
    __shared__ float red[256];
    __shared__ int redi[256];
    int tid = threadIdx.x;
    int i = blockIdx.x * 256 + tid;
    float lg = 0.f;
    int cv = 0;
    if (i < N) {
        cv = cnt[i];
        float c = (float)cv;
        dinv[i] = 1.f / sqrtf(c + 1.f);
        lg = logf(c + 1.f);
    }
    red[tid] = lg;
    redi[tid] = cv;
    __syncthreads();
    for (int s = 128; s > 0; s >>= 1) {
        if (tid < s) { red[tid] += red[tid + s]; redi[tid] += redi[tid + s]; }
        __syncthreads();
    }
    if (tid == 0) {
        gAtomicAdd(&scal[0], red[0]);
        bsum[blockIdx.x] = redi[0];
    }
}

__global__ void scanb_kernel(const int* __restrict__ bsum, int* __restrict__ bbase,
                             int* __restrict__ offs, int NB) {
    __shared__ int sh[128];
    int tid = threadIdx.x;
    int v = (tid < NB) ? bsum[tid] : 0;
    sh[tid] = v;
    __syncthreads();
    for (int d = 1; d < 128; d <<= 1) {
        int t = (tid >= d) ? sh[tid - d] : 0;
        __syncthreads();
        sh[tid] += t;
        __syncthreads();
    }
    if (tid < NB) bbase[tid] = sh[tid] - v;
    if (tid == 0) offs[NN] = EE;
}

__global__ void offs_kernel(const int* __restrict__ cnt, const int* __restrict__ bbase,
                            int* __restrict__ offs, int* __restrict__ cursor, int N) {
    __shared__ int sh[256];
    int tid = threadIdx.x;
    int i = blockIdx.x * 256 + tid;
    int v = (i < N) ? cnt[i] : 0;
    sh[tid] = v;
    __syncthreads();
    for (int d = 1; d < 256; d <<= 1) {
        int t = (tid >= d) ? sh[tid - d] : 0;
        __syncthreads();
        sh[tid] += t;
        __syncthreads();
    }
    int excl = sh[tid] - v + bbase[blockIdx.x];
    if (i < N) { offs[i] = excl; cursor[i] = excl; }
}

// CSR fill + xs prescale merged: items 0..EE-1 = fill; EE..EE+NN*80-1 = xs
__global__ void fill_xs_kernel(const int* __restrict__ row, const int* __restrict__ col,
                               int* __restrict__ cursor, int* __restrict__ csr,
                               const float* __restrict__ x, const float* __restrict__ gw,
                               const float* __restrict__ dinv, ushort* __restrict__ xs) {
    int idx = blockIdx.x * 256 + threadIdx.x;
    if (idx < EE) {
        int c = col[idx];
        int pos = atomicAdd(&cursor[c], 1);
        csr[pos] = row[idx];
    } else if (idx < EE + NN * 80) {
        int j = idx - EE;
        int n = j / 80, t = j % 80;
        float v = 0.f;
        if (t < FF) {
            float acc = 0.f;
#pragma unroll
            for (int k = 0; k < 6; k++) acc += x[n * 6 + k] * gw[k * FF + t];
            v = dinv[n] * acc;
        }
        xs[j] = f2bs(v);
    }
}

// one wave per node: lanes 0..39 gather ushort2 (features 2l, 2l+1), unroll 4
__global__ __launch_bounds__(64) void gcn_kernel(
    const ushort* __restrict__ xs, const float* __restrict__ dinv,
    const int* __restrict__ offs, const int* __restrict__ csr,
    const float* __restrict__ gcn_b, const int* __restrict__ cnt,
    const float* __restrict__ scal, float* __restrict__ o2,
    float* __restrict__ amp, float* __restrict__ att, int N) {
    int i = blockIdx.x;
    int lane = threadIdx.x;
    int s0 = offs[i], s1 = offs[i + 1];
    if (lane < 40) {
        float a0 = 0.f, a1 = 0.f;
        int k = s0;
        for (; k + 3 < s1; k += 4) {
            int r0 = csr[k], r1 = csr[k + 1], r2 = csr[k + 2], r3 = csr[k + 3];
            ushort2 v0 = *(const ushort2*)(xs + (size_t)r0 * 80 + 2 * lane);
            ushort2 v1 = *(const ushort2*)(xs + (size_t)r1 * 80 + 2 * lane);
            ushort2 v2 = *(const ushort2*)(xs + (size_t)r2 * 80 + 2 * lane);
            ushort2 v3 = *(const ushort2*)(xs + (size_t)r3 * 80 + 2 * lane);
            a0 += (bs2f(v0.x) + bs2f(v1.x)) + (bs2f(v2.x) + bs2f(v3.x));
            a1 += (bs2f(v0.y) + bs2f(v1.y)) + (bs2f(v2.y) + bs2f(v3.y));
        }
        for (; k < s1; k++) {
            int r0 = csr[k];
            ushort2 v0 = *(const ushort2*)(xs + (size_t)r0 * 80 + 2 * lane);
            a0 += bs2f(v0.x);
            a1 += bs2f(v0.y);
        }
        ushort2 vs = *(const ushort2*)(xs + (size_t)i * 80 + 2 * lane);
        a0 += bs2f(vs.x);
        a1 += bs2f(vs.y);
        float di = dinv[i];
        int t0 = 2 * lane, t1 = 2 * lane + 1;
        if (t0 < FF) o2[(size_t)i * 80 + t0] = di * a0 + gcn_b[t0];
        if (t1 < FF) o2[(size_t)i * 80 + t1] = di * a1 + gcn_b[t1];
    } else if (lane == 63) {
        float al = scal[0] / (float)N;
        float d = fmaxf((float)cnt[i], 1.f);
        float lg = logf(d + 1.f);
        amp[i] = lg / al;
        att[i] = al / lg;
    }
}

// ---------------- B-matrix prep (bf16, transposed: BT[col][k]) ----------------

#define S_UV (LL * NUV * KUV)
#define S_POST (LL * 240 * KPOST)
#define S_LIN (LL * 80 * KLIN)

__global__ void prep_bt_kernel(const float* __restrict__ pre_w, const float* __restrict__ pre_b,
                               const float* __restrict__ post_w, const float* __restrict__ lin_w,
                               ushort* __restrict__ BTuv, ushort* __restrict__ BTpost,
                               ushort* __restrict__ BTlin) {
    int idx = blockIdx.x * 256 + threadIdx.x;
    if (idx < S_UV) {
        int l = idx / (NUV * KUV);
        int r = idx % (NUV * KUV);
        int c = r / KUV, k = r % KUV;
        float v = 0.f;
        if (k < FF) {
            if (c < FF) v = pre_w[((size_t)l * 150 + k) * FF + c];
            else if (c >= 80 && c < 80 + FF) v = pre_w[((size_t)l * 150 + FF + k) * FF + (c - 80)];
        } else if (k == FF && c < FF) {
            v = pre_b[l * FF + c];  // bias fold: A col75 = 1.0
        }
        BTuv[idx] = f2bs(v);
    } else if (idx < S_UV + S_POST) {
        int j = idx - S_UV;
        int l = j / (240 * KPOST);
        int r = j % (240 * KPOST);
        int c = r / KPOST, k = r % KPOST;
        float v = 0.f;
        if (k < FF) {
            if (c < FF) v = post_w[((size_t)l * 975 + k) * FF + c];
        } else if (k < 375) {
            if (c < FF) v = post_w[((size_t)l * 975 + k) * FF + c];
            else if (c >= 80 && c < 80 + FF) v = post_w[((size_t)l * 975 + k + 300) * FF + (c - 80)];
            else if (c >= 160 && c < 160 + FF) v = post_w[((size_t)l * 975 + k + 600) * FF + (c - 160)];
        }
        BTpost[j] = f2bs(v);
    } else if (idx < S_UV + S_POST + S_LIN) {
        int j = idx - S_UV - S_POST;
        int l = j / (80 * KLIN);
        int r = j % (80 * KLIN);
        int c = r / KLIN, k = r % KLIN;
        float v = (c < FF && k < FF) ? lin_w[((size_t)l * FF + k) * FF + c] : 0.f;
        BTlin[j] = f2bs(v);
    }
}

// ---------------- fused BN + uv GEMM (streaming, 1 wave = 16 rows) ----------------
// BN scale/shift computed per-block from the 32 stat slots of the PREVIOUS layer.

__global__ __launch_bounds__(64) void uv_bn_kernel(
    const float* __restrict__ o2, const float* __restrict__ slots,
    const float* __restrict__ bg, const float* __restrict__ bb, int apply_bn,
    const ushort* __restrict__ BT, float* __restrict__ U, ushort* __restrict__ Vb,
    ushort* __restrict__ hagg) {
    __shared__ float ssL[160];
    int lane = threadIdx.x;
    int col16 = lane & 15, quad = lane >> 4;
    int n = blockIdx.x * 16 + col16;
    const float* orow = o2 + (size_t)n * 80;
    const ushort* bbase = BT + (size_t)col16 * KUV + quad * 8;

    if (apply_bn) {
        for (int c = lane; c < 80; c += 64) {
            if (c < FF) {
                float su = 0.f, sq = 0.f;
#pragma unroll 8
                for (int s = 0; s < 32; s++) {
                    su += slots[s * 160 + c];
                    sq += slots[s * 160 + 80 + c];
                }
                float mu = su * (1.f / (float)NN);
                float var = sq * (1.f / (float)NN) - mu * mu;
                float sc = bg[c] * rsqrtf(var + EPS);
                ssL[c] = sc;
                ssL[80 + c] = bb[c] - mu * sc;
            } else {
                ssL[c] = 0.f;
                ssL[80 + c] = 0.f;
            }
        }
        __syncthreads();
    }

    f32x4 acc[10];
#pragma unroll
    for (int i = 0; i < 10; i++) acc[i] = (f32x4){0.f, 0.f, 0.f, 0.f};

#pragma unroll
    for (int kt = 0; kt < 3; kt++) {
        int kb = kt * 32 + quad * 8;
        bf16x8 af;
        if (kb < 80) {
            float4 v0 = *(const float4*)(orow + kb);
            float4 v1 = *(const float4*)(orow + kb + 4);
            float vv[8] = {v0.x, v0.y, v0.z, v0.w, v1.x, v1.y, v1.z, v1.w};
#pragma unroll
            for (int j = 0; j < 8; j++) {
                int k = kb + j;
                float v = vv[j];
                if (apply_bn) v = fmaxf(v * ssL[k] + ssL[80 + k], 0.f);
                ushort b = (k < FF) ? f2bs(v) : (k == FF ? (ushort)0x3F80 : (ushort)0);
                af[j] = (short)b;
            }
            if (kb < FF) {
                // h-cols of hagg; forced values at cols 75..79 are overwritten by edge_agg
                *(bf16x8*)(hagg + (size_t)n * KPOST + kb) = af;
            }
        } else {
            af = (bf16x8){0, 0, 0, 0, 0, 0, 0, 0};
        }
#pragma unroll
        for (int nt = 0; nt < 10; nt++) {
            bf16x8 bfr = *(const bf16x8*)(bbase + nt * (16 * KUV) + kt * 32);
            acc[nt] = __builtin_amdgcn_mfma_f32_16x16x32_bf16(af, bfr, acc[nt], 0, 0, 0);
        }
    }
    int n0 = blockIdx.x * 16;
#pragma unroll
    for (int nt = 0; nt < 10; nt++) {
        int col = nt * 16 + col16;
#pragma unroll
        for (int r = 0; r < 4; r++) {
            int nn = n0 + quad * 4 + r;
            if (col < FF) U[(size_t)nn * 80 + col] = acc[nt][r];
            else if (col >= 80 && col < 80 + FF) Vb[(size_t)nn * 80 + (col - 80)] = f2bs(acc[nt][r]);
        }
    }
}

// ---------------- fused post GEMM + combine + lin GEMM + BN stats (1 wave) ----------------

__global__ __launch_bounds__(64) void post_lin_kernel(
    const ushort* __restrict__ A, const ushort* __restrict__ BT,
    const ushort* __restrict__ BL, const float* __restrict__ amp,
    const float* __restrict__ att, float* __restrict__ o2,
    float* __restrict__ slots) {
    __shared__ __align__(16) ushort olds[16 * 104];
    int lane = threadIdx.x;
    int col16 = lane & 15, quad = lane >> 4, kseg = quad * 8;
    int n0 = blockIdx.x * 16;
    const ushort* arow = A + (size_t)(n0 + col16) * KPOST + kseg;
    const ushort* bbase = BT + (size_t)col16 * KPOST + kseg;

    f32x4 acc[15];
#pragma unroll
    for (int i = 0; i < 15; i++) acc[i] = (f32x4){0.f, 0.f, 0.f, 0.f};

#pragma unroll 4
    for (int kt = 0; kt < 12; kt++) {
        bf16x8 af = *(const bf16x8*)(arow + kt * 32);
#pragma unroll
        for (int nt = 0; nt < 15; nt++) {
            bf16x8 bfr = *(const bf16x8*)(bbase + (size_t)nt * (16 * KPOST) + kt * 32);
            acc[nt] = __builtin_amdgcn_mfma_f32_16x16x32_bf16(af, bfr, acc[nt], 0, 0, 0);
        }
    }
    // combine with amp/att -> o (bf16) in LDS, A-fragment layout
    float ampv[4], attv[4];
#pragma unroll
    for (int r = 0; r < 4; r++) {
        int n = n0 + quad * 4 + r;
        ampv[r] = amp[n];
        attv[r] = att[n];
    }
#pragma unroll
    for (int g = 0; g < 5; g++) {
        int col = g * 16 + col16;
#pragma unroll
        for (int r = 0; r < 4; r++) {
            float ov = acc[g][r] + ampv[r] * acc[g + 5][r] + attv[r] * acc[g + 10][r];
            olds[(quad * 4 + r) * 104 + col] = (col < FF) ? f2bs(ov) : (ushort)0;
        }
    }
    // zero K-pad cols 80..95
    *(ushort4*)(olds + (lane >> 2) * 104 + 80 + (lane & 3) * 4) = (ushort4){0, 0, 0, 0};
    __syncthreads();

    // lin GEMM (K=96)
    f32x4 acc2[5];
#pragma unroll
    for (int i = 0; i < 5; i++) acc2[i] = (f32x4){0.f, 0.f, 0.f, 0.f};
    const ushort* blbase = BL + (size_t)col16 * KLIN + kseg;
#pragma unroll
    for (int kt = 0; kt < 3; kt++) {
        bf16x8 af = *(const bf16x8*)(olds + col16 * 104 + kt * 32 + kseg);
#pragma unroll
        for (int nt = 0; nt < 5; nt++) {
            bf16x8 bfr = *(const bf16x8*)(blbase + nt * (16 * KLIN) + kt * 32);
            acc2[nt] = __builtin_amdgcn_mfma_f32_16x16x32_bf16(af, bfr, acc2[nt], 0, 0, 0);
        }
    }
    // epilogue: store o2 + BN partial sums (fan into 32 slots)
    float* slot = slots + (blockIdx.x & 31) * 160;
#pragma unroll
    for (int nt = 0; nt < 5; nt++) {
        int col = nt * 16 + col16;
        float s = 0.f, q = 0.f;
#pragma unroll
        for (int r = 0; r < 4; r++) {
            int n = n0 + quad * 4 + r;
            float v = acc2[nt][r];
            if (col < FF) {
                o2[(size_t)n * 80 + col] = v;
                s += v;
                q += v * v;
            }
        }
        s += __shfl_xor(s, 16); s += __shfl_xor(s, 32);
        q += __shfl_xor(q, 16); q += __shfl_xor(q, 32);
        if (lane < 16 && col < FF) {
            gAtomicAdd(&slot[col], s);
            gAtomicAdd(&slot[80 + col], q);
        }
    }
}

// ---------------- edge aggregation: one wave per node, ushort2 gathers, unroll 4 ----------------

__global__ __launch_bounds__(64) void edge_agg_kernel(
    const float* __restrict__ U, const ushort* __restrict__ V,
    const int* __restrict__ offs, const int* __restrict__ csr,
    const int* __restrict__ cnt, ushort* __restrict__ hagg) {
    int i = blockIdx.x;
    int lane = threadIdx.x;
    int s0 = offs[i], s1 = offs[i + 1];
    if (lane < 40) {
        float2 uiv = *(const float2*)(U + (size_t)i * 80 + 2 * lane);
        float ui0 = uiv.x, ui1 = uiv.y;
        float sa0 = 0.f, sq0 = 0.f, mn0 = 1e30f, mx0 = -1e30f;
        float sa1 = 0.f, sq1 = 0.f, mn1 = 1e30f, mx1 = -1e30f;
        int k = s0;
        for (; k + 3 < s1; k += 4) {
            int r0 = csr[k], r1 = csr[k + 1], r2 = csr[k + 2], r3 = csr[k + 3];
            ushort2 v0 = *(const ushort2*)(V + (size_t)r0 * 80 + 2 * lane);
            ushort2 v1 = *(const ushort2*)(V + (size_t)r1 * 80 + 2 * lane);
            ushort2 v2 = *(const ushort2*)(V + (size_t)r2 * 80 + 2 * lane);
            ushort2 v3 = *(const ushort2*)(V + (size_t)r3 * 80 + 2 * lane);
            float a0 = ui0 + bs2f(v0.x), b0 = ui0 + bs2f(v1.x);
            float c0 = ui0 + bs2f(v2.x), d0 = ui0 + bs2f(v3.x);
            float a1 = ui1 + bs2f(v0.y), b1 = ui1 + bs2f(v1.y);
            float c1 = ui1 + bs2f(v2.y), d1 = ui1 + bs2f(v3.y);
            sa0 += (a0 + b0) + (c0 + d0);
            sq0 += (a0 * a0 + b0 * b0) + (c0 * c0 + d0 * d0);
            mn0 = fminf(mn0, fminf(fminf(a0, b0), fminf(c0, d0)));
            mx0 = fmaxf(mx0, fmaxf(fmaxf(a0, b0), fmaxf(c0, d0)));
            sa1 += (a1 + b1) + (c1 + d1);
            sq1 += (a1 * a1 + b1 * b1) + (c1 * c1 + d1 * d1);
            mn1 = fminf(mn1, fminf(fminf(a1, b1), fminf(c1, d1)));
            mx1 = fmaxf(mx1, fmaxf(fmaxf(a1, b1), fmaxf(c1, d1)));
        }
        for (; k < s1; k++) {
            int r0 = csr[k];
            ushort2 v0 = *(const ushort2*)(V + (size_t)r0 * 80 + 2 * lane);
            float a0 = ui0 + bs2f(v0.x);
            float a1 = ui1 + bs2f(v0.y);
            sa0 += a0; sq0 += a0 * a0; mn0 = fminf(mn0, a0); mx0 = fmaxf(mx0, a0);
            sa1 += a1; sq1 += a1 * a1; mn1 = fminf(mn1, a1); mx1 = fmaxf(mx1, a1);
        }
        int c = cnt[i];
        float cc = fmaxf((float)c, 1.f);
        ushort* a = hagg + (size_t)i * KPOST + FF;
        int t0 = 2 * lane, t1 = 2 * lane + 1;
        {
            float mean = sa0 / cc;
            float stdv = sqrtf(fmaxf(sq0 / cc - mean * mean, 0.f) + EPS);
            if (c == 0) { mn0 = 0.f; mx0 = 0.f; }
            if (t0 < FF) {
                a[t0] = f2bs(mean);
                a[FF + t0] = f2bs(mn0);
                a[2 * FF + t0] = f2bs(mx0);
                a[3 * FF + t0] = f2bs(stdv);
            }
        }
        {
            float mean = sa1 / cc;
            float stdv = sqrtf(fmaxf(sq1 / cc - mean * mean, 0.f) + EPS);
            if (c == 0) { mn1 = 0.f; mx1 = 0.f; }
            if (t1 < FF) {
                a[t1] = f2bs(mean);
                a[FF + t1] = f2bs(mn1);
                a[2 * FF + t1] = f2bs(mx1);
                a[3 * FF + t1] = f2bs(stdv);
            }
        }
    } else if (lane >= 48 && lane < 57) {
        hagg[(size_t)i * KPOST + 375 + (lane - 48)] = 0;  // K-pad
    }
}

// ---------------- pooling (BN inline, slot reduce per block) + final MLP ----------------

__global__ void pool_kernel(const float* __restrict__ o2, const float* __restrict__ slots,
                            const float* __restrict__ bg, const float* __restrict__ bb,
                            const int* __restrict__ batch, float* __restrict__ g, int N) {
    __shared__ float acc[GG * FF];
    __shared__ float ssL[160];
    int tid = threadIdx.x;
    int n0 = blockIdx.x * 64;
    int n1 = min(n0 + 64, N);
    if (n0 >= N) return;
    for (int c = tid; c < 80; c += 256) {
        if (c < FF) {
            float su = 0.f, sq = 0.f;
#pragma unroll 8
            for (int s = 0; s < 32; s++) {
                su += slots[s * 160 + c];
                sq += slots[s * 160 + 80 + c];
            }
            float mu = su * (1.f / (float)NN);
            float var = sq * (1.f / (float)NN) - mu * mu;
            float sc = bg[c] * rsqrtf(var + EPS);
            ssL[c] = sc;
            ssL[80 + c] = bb[c] - mu * sc;
        } else {
            ssL[c] = 0.f;
            ssL[80 + c] = 0.f;
        }
    }
    int g0 = batch[n0];
    int g1 = batch[n1 - 1];
    int range = g1 - g0 + 1;
    for (int i = tid; i < range * FF; i += 256) acc[i] = 0.f;
    __syncthreads();
    int rows = n1 - n0;
    for (int idx = tid; idx < rows * FF; idx += 256) {
        int r = idx / FF, c = idx % FF;
        int n = n0 + r;
        float val = fmaxf(o2[(size_t)n * 80 + c] * ssL[c] + ssL[80 + c], 0.f);
        gAtomicAdd(&acc[(batch[n] - g0) * FF + c], val);
    }
    __syncthreads();
    for (int i = tid; i < range * FF; i += 256) gAtomicAdd(&g[g0 * FF + i], acc[i]);
}

__global__ void mlp_kernel(const float* __restrict__ g,
                           const float* __restrict__ w1, const float* __restrict__ b1,
                           const float* __restrict__ w2, const float* __restrict__ b2,
                           const float* __restrict__ w3, const float* __restrict__ b3,
                           float* __restrict__ out) {
    __shared__ float gr[FF], h1[50], h2[25];
    int gi = blockIdx.x, t = threadIdx.x;
    for (int j = t; j < FF; j += 64) gr[j] = g[gi * FF + j];
    __syncthreads();
    if (t < 50) {
        float a = b1[t];
        for (int k = 0; k < FF; k++) a += gr[k] * w1[k * 50 + t];
        h1[t] = fmaxf(a, 0.f);
    }
    __syncthreads();
    if (t < 25) {
        float a = b2[t];
        for (int k = 0; k < 50; k++) a += h1[k] * w2[k * 25 + t];
        h2[t] = fmaxf(a, 0.f);
    }
    __syncthreads();
    if (t < 10) {
        float a = b3[t];
        for (int k = 0; k < 25; k++) a += h2[k] * w3[k * 10 + t];
        out[gi * 10 + t] = a;
    }
}

// ---------------- launch ----------------

extern "C" void kernel_launch(void* const* d_in, const int* in_sizes, int n_in,
                              void* d_out, int out_size, void* d_ws, size_t ws_size,
                              hipStream_t stream) {
    const float* x = (const float*)d_in[0];
    const int* ei = (const int*)d_in[1];
    const int* batch = (const int*)d_in[2];
    const float* gcn_w = (const float*)d_in[3];
    const float* gcn_b = (const float*)d_in[4];
    const float* pre_w = (const float*)d_in[5];
    const float* pre_b = (const float*)d_in[6];
    const float* post_w = (const float*)d_in[7];
    const float* lin_w = (const float*)d_in[9];
    const float* bn_g = (const float*)d_in[11];
    const float* bn_b = (const float*)d_in[12];
    const float* w1 = (const float*)d_in[13];
    const float* b1 = (const float*)d_in[14];
    const float* w2 = (const float*)d_in[15];
    const float* b2 = (const float*)d_in[16];
    const float* w3 = (const float*)d_in[17];
    const float* b3 = (const float*)d_in[18];
    float* out = (float*)d_out;

    const int* row = ei;
    const int* col = ei + EE;

    char* ws = (char*)d_ws;
    size_t off = 0;
    auto alloc = [&](size_t bytes) {
        char* p = ws + off;
        off += (bytes + 255) & ~(size_t)255;
        return p;
    };
    // zero-region: cnt + scal + gbuf adjacent, single memset
    size_t z0 = off;
    int* cnt = (int*)alloc(NN * 4);
    float* scal = (float*)alloc((1 + LL * 32 * 160) * 4);  // [0]=sumlog; slots[5][32][160]
    float* gbuf = (float*)alloc(GG * FF * 4);
    size_t z1 = off;
    float* slotbase = scal + 1;
    int* offs = (int*)alloc((NN + 1) * 4);
    int* cursor = (int*)alloc(NN * 4);
    int* csr = (int*)alloc(EE * 4);
    int* bsum = (int*)alloc(128 * 4);
    int* bbase = (int*)alloc(128 * 4);
    float* dinv = (float*)alloc(NN * 4);
    float* amp = (float*)alloc(NN * 4);
    float* att = (float*)alloc(NN * 4);
    float* o2 = (float*)alloc((size_t)NN * 80 * 4);
    float* ubuf = (float*)alloc((size_t)NN * 80 * 4);
    ushort* vbuf = (ushort*)alloc((size_t)NN * 80 * 2);  // xs in setup, V in layers
    ushort* hagg = (ushort*)alloc((size_t)NN * KPOST * 2);
    ushort* BTuv = (ushort*)alloc((size_t)S_UV * 2);
    ushort* BTpost = (ushort*)alloc((size_t)S_POST * 2);
    ushort* BTlin = (ushort*)alloc((size_t)S_LIN * 2);

    hipMemsetAsync(ws + z0, 0, z1 - z0, stream);

    const int B = 256;
    const int NB = (NN + 255) / 256;  // 79
    count_kernel<<<(EE + B - 1) / B, B, 0, stream>>>(col, cnt, EE);
    dinv_partial_kernel<<<NB, B, 0, stream>>>(cnt, dinv, scal, bsum, NN);
    scanb_kernel<<<1, 128, 0, stream>>>(bsum, bbase, offs, NB);
    offs_kernel<<<NB, B, 0, stream>>>(cnt, bbase, offs, cursor, NN);
    fill_xs_kernel<<<(EE + NN * 80 + B - 1) / B, B, 0, stream>>>(row, col, cursor, csr,
                                                                 x, gcn_w, dinv, vbuf);
    gcn_kernel<<<NN, 64, 0, stream>>>(vbuf, dinv, offs, csr, gcn_b, cnt, scal,
                                      o2, amp, att, NN);
    {
        int tot = S_UV + S_POST + S_LIN;
        prep_bt_kernel<<<(tot + B - 1) / B, B, 0, stream>>>(pre_w, pre_b, post_w, lin_w,
                                                            BTuv, BTpost, BTlin);
    }

    const int GS = NN / 16;  // 1250 single-wave blocks (exact)
    for (int l = 0; l < LL; l++) {
        float* slots_prev = slotbase + (l - 1) * 32 * 160;  // unused when l==0
        float* slots = slotbase + l * 32 * 160;
        int lp = (l > 0) ? (l - 1) : 0;
        int ab = (l > 0) ? 1 : 0;
        const float* sp = (l == 0) ? slotbase : slots_prev;

        uv_bn_kernel<<<GS, 64, 0, stream>>>(o2, sp, bn_g + lp * FF, bn_b + lp * FF, ab,
                                            BTuv + (size_t)l * NUV * KUV, ubuf, vbuf, hagg);
        edge_agg_kernel<<<NN, 64, 0, stream>>>(ubuf, vbuf, offs, csr, cnt, hagg);
        post_lin_kernel<<<GS, 64, 0, stream>>>(hagg, BTpost + (size_t)l * 240 * KPOST,
                                               BTlin + (size_t)l * 80 * KLIN, amp, att,
                                               o2, slots);
    }

    pool_kernel<<<(NN + 63) / 64, 256, 0, stream>>>(o2, slotbase + (LL - 1) * 32 * 160,
                                                    bn_g + (LL - 1) * FF, bn_b + (LL - 1) * FF,
                                                    batch, gbuf, NN);
    mlp_kernel<<<GG, 64, 0, stream>>>(gbuf, w1, b1, w2, b2, w3, b3, out);
}